// Round 14
// baseline (86.218 us; speedup 1.0000x reference)
//
#include <hip/hip_runtime.h>
#include <cstddef>
#include <cstdint>

#define F 128
#define LDK 136  // hid LDS row stride in shorts (272B, 16B aligned)
#define AGG_BLOCKS 2048
#define MID_BLOCKS 64

typedef __attribute__((ext_vector_type(8))) short short8;
typedef __attribute__((ext_vector_type(4))) float f32x4;

__device__ __forceinline__ short f2bf(float f) {
  uint32_t u = __float_as_uint(f);
  uint32_t r = u + 0x7FFFu + ((u >> 16) & 1u);  // round-to-nearest-even
  return (short)(r >> 16);
}
__device__ __forceinline__ float bf2f(short h) {
  return __uint_as_float(((uint32_t)(uint16_t)h) << 16);
}

// ---------------- setup: Hamilton pack (blocks 0..15) + rowptr + cv pairs ----------------
// H[row][col] = sign * w[row&31][( (row>>5)^(col>>5) )*32 + (col&31)], neg mask 0x284E
// Hpk layout: [m(2)][part(2: hi,lo)][kt(4)][ct(8)][lane(64)][j(8)]  (128 KB total)
__global__ __launch_bounds__(256) void setup_kernel(
    const float* __restrict__ w1, const float* __restrict__ w2,
    short* __restrict__ Hpk, const int* __restrict__ adj_row,
    const int* __restrict__ adj_col, const float* __restrict__ adj_val,
    int* __restrict__ rowptr, uint2* __restrict__ cv, int E, int N) {
  if (blockIdx.x < 16) {
    int idx = blockIdx.x * 256 + threadIdx.x;  // 4096: (m,kt,ct,lane)
    int m = idx >> 11;
    int kt = (idx >> 9) & 3;
    int ct = (idx >> 6) & 7;
    int l = idx & 63;
    int col = ct * 16 + (l & 15);
    const float* w = m ? w2 : w1;
    short hi[8], lo[8];
#pragma unroll
    for (int j = 0; j < 8; ++j) {
      int row = kt * 32 + (l >> 4) * 8 + j;  // k index of B
      int rb = row >> 5, cb = col >> 5;
      int neg = (0x284E >> (cb * 4 + rb)) & 1;
      float v = w[(row & 31) * 128 + (rb ^ cb) * 32 + (col & 31)];
      v = neg ? -v : v;
      short h = f2bf(v);
      hi[j] = h;
      lo[j] = f2bf(v - bf2f(h));
    }
    size_t b0 = ((((size_t)m * 2 + 0) * 4 + kt) * 8 + ct) * 64 + l;
    size_t b1 = ((((size_t)m * 2 + 1) * 4 + kt) * 8 + ct) * 64 + l;
    *(short8*)&Hpk[b0 * 8] = *(short8*)hi;
    *(short8*)&Hpk[b1 * 8] = *(short8*)lo;
  } else {
    int e = (blockIdx.x - 16) * 256 + threadIdx.x;
    if (e >= E) return;
    cv[e] = make_uint2((uint32_t)adj_col[e], __float_as_uint(adj_val[e]));
    int r = adj_row[e];
    int rprev = (e == 0) ? -1 : adj_row[e - 1];
    for (int q = rprev + 1; q <= r; ++q) rowptr[q] = e;
    if (e == E - 1) {
      for (int q = r + 1; q <= N; ++q) rowptr[q] = E;
    }
  }
}

// ---------------- fused MFMA GEMM: out2 = tanh(X @ H1) @ H2, bf16 out ----------------
// 256 threads (4 waves x 16 rows). B-frags staged in shared LDS in 32 KB
// HALF-matrix phases (kt-pairs) -> 49.4 KB LDS total -> 3 blocks/CU.
__global__ __launch_bounds__(256) void gemm_mfma(
    const float* __restrict__ input, const short* __restrict__ Hpk,
    short* __restrict__ out2b, int N) {
  __shared__ short Hs[16384];         // 32 KB: half-matrix frags [part][ktl][ct][lane][j]
  __shared__ short lds[4][16 * LDK];  // 17.4 KB per-wave hid tiles
  const int t = threadIdx.x;
  const int w = t >> 6, l = t & 63;
  const int lr = l & 15, lg = l >> 4;
  const int grow0 = blockIdx.x * 64 + w * 16;
  short* hid = &lds[w][0];

#define STAGE_HALF(m, P)                                             \
  {                                                                  \
    const int base = ((m) * 8 + 2 * (P)) * 512;                      \
    _Pragma("unroll") for (int i = 0; i < 8; ++i) {                  \
      int idx = i * 256 + t;                                         \
      int src = idx + base + (idx >> 10) * 1024;                     \
      *(short8*)&Hs[idx * 8] = *(const short8*)&Hpk[src * 8];        \
    }                                                                \
  }

#define GEMM_HALF(afrag, P)                                                          \
  {                                                                                  \
    _Pragma("unroll") for (int ktl = 0; ktl < 2; ++ktl) {                            \
      _Pragma("unroll") for (int ct = 0; ct < 8; ++ct) {                             \
        short8 bh = *(const short8*)&Hs[((ktl * 8 + ct) * 64 + l) * 8];              \
        short8 bl = *(const short8*)&Hs[(((2 + ktl) * 8 + ct) * 64 + l) * 8];        \
        acc[ct] = __builtin_amdgcn_mfma_f32_16x16x32_bf16(afrag[2 * (P) + ktl], bl,  \
                                                          acc[ct], 0, 0, 0);         \
        acc[ct] = __builtin_amdgcn_mfma_f32_16x16x32_bf16(afrag[2 * (P) + ktl], bh,  \
                                                          acc[ct], 0, 0, 0);         \
      }                                                                              \
    }                                                                                \
  }

  // A1 fragments (hi only) from global f32
  short8 a1h[4];
  {
    int arow = grow0 + lr;
    if (arow >= N) arow = N - 1;
    const float* xr = &input[(size_t)arow * F];
#pragma unroll
    for (int kt = 0; kt < 4; ++kt) {
      float xv[8];
      *(float4*)&xv[0] = *(const float4*)&xr[kt * 32 + lg * 8];
      *(float4*)&xv[4] = *(const float4*)&xr[kt * 32 + lg * 8 + 4];
#pragma unroll
      for (int j = 0; j < 8; ++j) ((short*)&a1h[kt])[j] = f2bf(xv[j]);
    }
  }

  f32x4 acc[8];
#pragma unroll
  for (int ct = 0; ct < 8; ++ct) acc[ct] = (f32x4){0.f, 0.f, 0.f, 0.f};

  STAGE_HALF(0, 0)
  __syncthreads();
  GEMM_HALF(a1h, 0)
  __syncthreads();
  STAGE_HALF(0, 1)
  __syncthreads();
  GEMM_HALF(a1h, 1)

  // hid = tanh(acc) -> per-wave LDS row-major (C layout: row=lg*4+r, col=ct*16+lr)
#pragma unroll
  for (int ct = 0; ct < 8; ++ct)
#pragma unroll
    for (int r = 0; r < 4; ++r)
      hid[(lg * 4 + r) * LDK + ct * 16 + lr] = f2bf(tanhf(acc[ct][r]));

  // A2 fragments: vectorized b128 reads from own wave's tile (row=lr, k contiguous)
  short8 a2h[4];
#pragma unroll
  for (int kt = 0; kt < 4; ++kt)
    a2h[kt] = *(short8*)&hid[lr * LDK + kt * 32 + lg * 8];

#pragma unroll
  for (int ct = 0; ct < 8; ++ct) acc[ct] = (f32x4){0.f, 0.f, 0.f, 0.f};

  __syncthreads();  // all waves done reading H1 half
  STAGE_HALF(1, 0)
  __syncthreads();
  GEMM_HALF(a2h, 0)
  __syncthreads();
  STAGE_HALF(1, 1)
  __syncthreads();
  GEMM_HALF(a2h, 1)

  // epilogue: bf16 pack -> per-wave LDS, then coalesced row stores
#pragma unroll
  for (int ct = 0; ct < 8; ++ct)
#pragma unroll
    for (int r = 0; r < 4; ++r)
      hid[(lg * 4 + r) * LDK + ct * 16 + lr] = f2bf(acc[ct][r]);
#pragma unroll
  for (int i = 0; i < 4; ++i) {
    int chunk = i * 64 + l;
    int row = chunk >> 4, pos = chunk & 15;
    int grow = grow0 + row;
    if (grow < N)
      *(short8*)&out2b[(size_t)grow * F + pos * 8] = *(short8*)&hid[row * LDK + pos * 8];
  }
#undef STAGE_HALF
#undef GEMM_HALF
}

// ---------------- segment-sum SpMM + fused BN stats ----------------
// 2 rows/wave interleaved (8 gathers in flight); 16 lanes/edge dwordx4; clamped
// quads; next-pair rowptr prefetch; grid-stride over row pairs.
__global__ __launch_bounds__(256) void agg_rows7(
    const uint32_t* __restrict__ out2u, const int* __restrict__ rowptr,
    const uint2* __restrict__ cv, float* __restrict__ agg,
    float* __restrict__ partials, uint32_t* __restrict__ ctr, int N) {
  const int t = threadIdx.x;
  const int w = t >> 6, lane = t & 63;
  const int sub = lane >> 4;
  const int fl4 = (lane & 15) * 4;
  const int wid = blockIdx.x * 4 + w;
  const int nw = gridDim.x * 4;
  if (blockIdx.x == 0 && t == 0) *ctr = 0u;  // reset for midfin's last-block pattern
  float ssum[8], ssq[8];
#pragma unroll
  for (int j = 0; j < 8; ++j) { ssum[j] = 0.f; ssq[j] = 0.f; }

  int pr = wid;
  bool active = pr * 2 < N;
  int sA = 0, eAe = 0, eBe = 0;
  if (active) {
    sA = rowptr[pr * 2];
    eAe = rowptr[pr * 2 + 1];
    eBe = (pr * 2 + 1 < N) ? rowptr[pr * 2 + 2] : eAe;
  }
  while (active) {
    const int prn = pr + nw;
    const bool actn = prn * 2 < N;
    int sAn = 0, eAen = 0, eBen = 0;
    if (actn) {
      sAn = rowptr[prn * 2];
      eAen = rowptr[prn * 2 + 1];
      eBen = (prn * 2 + 1 < N) ? rowptr[prn * 2 + 2] : eAen;
    }
    const int rowA = pr * 2;
    const bool hasB = rowA + 1 < N;
    const int sB = eAe;

    float accA[8], accB[8];
#pragma unroll
    for (int j = 0; j < 8; ++j) { accA[j] = 0.f; accB[j] = 0.f; }

    int eA = sA, eB = sB;
    while (eA < eAe || eB < eBe) {
      float vA[4], vB[4];
      uint32_t cA[4], cB[4];
#pragma unroll
      for (int q = 0; q < 4; ++q) {
        int ee = eA + q * 4 + sub;
        bool val = ee < eAe;
        int idx = val ? ee : (eAe - 1);
        idx = idx < 0 ? 0 : idx;
        uint2 p = cv[idx];
        cA[q] = p.x;
        vA[q] = val ? __uint_as_float(p.y) : 0.f;
      }
#pragma unroll
      for (int q = 0; q < 4; ++q) {
        int ee = eB + q * 4 + sub;
        bool val = ee < eBe;
        int idx = val ? ee : (eBe - 1);
        idx = idx < 0 ? 0 : idx;
        uint2 p = cv[idx];
        cB[q] = p.x;
        vB[q] = val ? __uint_as_float(p.y) : 0.f;
      }
      uint4 uA[4], uB[4];
#pragma unroll
      for (int q = 0; q < 4; ++q)
        uA[q] = *(const uint4*)&out2u[(size_t)(cA[q] * 64u + fl4)];
#pragma unroll
      for (int q = 0; q < 4; ++q)
        uB[q] = *(const uint4*)&out2u[(size_t)(cB[q] * 64u + fl4)];
#pragma unroll
      for (int q = 0; q < 4; ++q) {
#pragma unroll
        for (int k = 0; k < 4; ++k) {
          uint32_t ua = ((const uint32_t*)&uA[q])[k];
          uint32_t ub = ((const uint32_t*)&uB[q])[k];
          accA[2 * k]     = fmaf(vA[q], __uint_as_float(ua << 16), accA[2 * k]);
          accA[2 * k + 1] = fmaf(vA[q], __uint_as_float(ua & 0xFFFF0000u), accA[2 * k + 1]);
          accB[2 * k]     = fmaf(vB[q], __uint_as_float(ub << 16), accB[2 * k]);
          accB[2 * k + 1] = fmaf(vB[q], __uint_as_float(ub & 0xFFFF0000u), accB[2 * k + 1]);
        }
      }
      eA += 16;
      eB += 16;
    }
#pragma unroll
    for (int j = 0; j < 8; ++j) {
      accA[j] += __shfl_xor(accA[j], 16, 64);
      accA[j] += __shfl_xor(accA[j], 32, 64);
      accB[j] += __shfl_xor(accB[j], 16, 64);
      accB[j] += __shfl_xor(accB[j], 32, 64);
    }
    if (sub == 0) {
      *(float4*)&agg[(size_t)rowA * F + fl4 * 2] = make_float4(accA[0], accA[1], accA[2], accA[3]);
      *(float4*)&agg[(size_t)rowA * F + fl4 * 2 + 4] = make_float4(accA[4], accA[5], accA[6], accA[7]);
#pragma unroll
      for (int j = 0; j < 8; ++j) {
        ssum[j] += accA[j];
        ssq[j] = fmaf(accA[j], accA[j], ssq[j]);
      }
      if (hasB) {
        *(float4*)&agg[(size_t)(rowA + 1) * F + fl4 * 2] = make_float4(accB[0], accB[1], accB[2], accB[3]);
        *(float4*)&agg[(size_t)(rowA + 1) * F + fl4 * 2 + 4] = make_float4(accB[4], accB[5], accB[6], accB[7]);
#pragma unroll
        for (int j = 0; j < 8; ++j) {
          ssum[j] += accB[j];
          ssq[j] = fmaf(accB[j], accB[j], ssq[j]);
        }
      }
    }
    pr = prn;
    sA = sAn; eAe = eAen; eBe = eBen;
    active = actn;
  }

  __shared__ float ls[4][128];
  __shared__ float lq[4][128];
  if (sub == 0) {
#pragma unroll
    for (int j = 0; j < 8; ++j) {
      ls[w][fl4 * 2 + j] = ssum[j];
      lq[w][fl4 * 2 + j] = ssq[j];
    }
  }
  __syncthreads();
  if (t < 128) {
    float S = ls[0][t] + ls[1][t] + ls[2][t] + ls[3][t];
    float Q = lq[0][t] + lq[1][t] + lq[2][t] + lq[3][t];
    float* dst = &partials[(size_t)blockIdx.x * 256];
    dst[t] = S;
    dst[128 + t] = Q;
  }
}

// ---------------- stats: mid-reduce + last-block finalize (one kernel) ----------------
__global__ __launch_bounds__(256) void midfin(
    const float* __restrict__ partials, float* __restrict__ mid,
    const float* __restrict__ gamma, const float* __restrict__ beta,
    float* __restrict__ ss, uint32_t* __restrict__ ctr, float invN, int nb) {
  const int k = blockIdx.x, t = threadIdx.x;
  const int per = nb / MID_BLOCKS;
  float s = 0.f;
#pragma unroll 4
  for (int i = 0; i < per; ++i)
    s += partials[(size_t)(k * per + i) * 256 + t];
  mid[(size_t)k * 256 + t] = s;
  __threadfence();   // release: mid visible before the counter bump
  __syncthreads();
  __shared__ bool last;
  if (t == 0) last = (atomicAdd(ctr, 1u) == MID_BLOCKS - 1);
  __syncthreads();
  if (!last) return;
  __threadfence();   // acquire: see all other blocks' mid
  float s2 = 0.f;
#pragma unroll 8
  for (int b = 0; b < MID_BLOCKS; ++b) s2 += mid[(size_t)b * 256 + t];
  __shared__ float tot[256];
  tot[t] = s2;
  __syncthreads();
  if (t < 128) {
    float mean = tot[t] * invN;
    float var = tot[128 + t] * invN - mean * mean;
    float inv = rsqrtf(var + 1e-5f);
    float sc = gamma[t] * inv;
    ss[t] = sc;
    ss[128 + t] = beta[t] - mean * sc;
  }
}

__global__ __launch_bounds__(256) void bn_apply(
    float* __restrict__ out, const float* __restrict__ ss, int total4) {
  int idx = blockIdx.x * 256 + threadIdx.x;
  if (idx >= total4) return;
  int f4 = (idx & 31) * 4;
  float4 v = *(float4*)&out[(size_t)idx * 4];
  float4 sc = *(const float4*)&ss[f4];
  float4 sh = *(const float4*)&ss[128 + f4];
  v.x = fmaf(v.x, sc.x, sh.x);
  v.y = fmaf(v.y, sc.y, sh.y);
  v.z = fmaf(v.z, sc.z, sh.z);
  v.w = fmaf(v.w, sc.w, sh.w);
  *(float4*)&out[(size_t)idx * 4] = v;
}

// ---------------- launch ----------------
// ws layout (bytes):
//   [0,        131072)   Hpk bf16 fragments (128 KB)
//   [131072,   132096)   ss: scale[128], shift[128]
//   [132096,   132160)   ctr (uint32, reset by agg each call)
//   [132608,   2229760)  partials (AGG_BLOCKS x 256 floats, 2 MB)
//   [2229760,  2295296)  mid: MID_BLOCKS x 256 floats
//   [2295296,  2500096)  rowptr (N+1 ints, padded)
//   [2500096,  +E*8)     cv pairs (col,val) per edge
//   [then]               out2 bf16 [N*128]
extern "C" void kernel_launch(void* const* d_in, const int* in_sizes, int n_in,
                              void* d_out, int out_size, void* d_ws, size_t ws_size,
                              hipStream_t stream) {
  (void)n_in; (void)out_size; (void)ws_size;
  const float* input  = (const float*)d_in[0];
  const int*  adj_row = (const int*)d_in[1];
  const int*  adj_col = (const int*)d_in[2];
  const float* adj_val = (const float*)d_in[3];
  const float* w1 = (const float*)d_in[4];
  const float* w2 = (const float*)d_in[5];
  const float* gamma = (const float*)d_in[6];
  const float* beta  = (const float*)d_in[7];
  const int N = in_sizes[0] / F;
  const int E = in_sizes[1];

  char* ws = (char*)d_ws;
  short* Hpk = (short*)(ws);
  float* ss = (float*)(ws + 131072);
  uint32_t* ctr = (uint32_t*)(ws + 132096);
  float* partials = (float*)(ws + 132608);
  float* mid = (float*)(ws + 2229760);
  int* rowptr = (int*)(ws + 2295296);
  uint2* cv = (uint2*)(ws + 2500096);
  size_t cv_bytes = ((size_t)E * 8 + 511) & ~(size_t)511;
  short* out2b = (short*)(ws + 2500096 + cv_bytes);
  float* agg = (float*)d_out;

  setup_kernel<<<16 + (E + 255) / 256, 256, 0, stream>>>(
      w1, w2, Hpk, adj_row, adj_col, adj_val, rowptr, cv, E, N);
  gemm_mfma<<<(N + 63) / 64, 256, 0, stream>>>(input, Hpk, out2b, N);
  agg_rows7<<<AGG_BLOCKS, 256, 0, stream>>>(
      (const uint32_t*)out2b, rowptr, cv, agg, partials, ctr, N);
  midfin<<<MID_BLOCKS, 256, 0, stream>>>(partials, mid, gamma, beta, ss, ctr,
                                         1.0f / (float)N, AGG_BLOCKS);
  bn_apply<<<(N * 32 + 255) / 256, 256, 0, stream>>>(agg, ss, N * 32);
}

// Round 15
// 82.714 us; speedup vs baseline: 1.0424x; 1.0424x over previous
//
#include <hip/hip_runtime.h>
#include <cstddef>
#include <cstdint>

#define F 128
#define LDK 136  // hid LDS row stride in shorts (272B, 16B aligned)
#define AGG_BLOCKS 2048
#define MID_BLOCKS 64

typedef __attribute__((ext_vector_type(8))) short short8;
typedef __attribute__((ext_vector_type(4))) float f32x4;

__device__ __forceinline__ short f2bf(float f) {
  uint32_t u = __float_as_uint(f);
  uint32_t r = u + 0x7FFFu + ((u >> 16) & 1u);  // round-to-nearest-even
  return (short)(r >> 16);
}
__device__ __forceinline__ float bf2f(short h) {
  return __uint_as_float(((uint32_t)(uint16_t)h) << 16);
}

// ---------------- setup: Hamilton pack (blocks 0..15) + rowptr + cv pairs ----------------
// H[row][col] = sign * w[row&31][( (row>>5)^(col>>5) )*32 + (col&31)], neg mask 0x284E
// Hpk layout: [m(2)][part(2: hi,lo)][kt(4)][ct(8)][lane(64)][j(8)]  (128 KB total)
__global__ __launch_bounds__(256) void setup_kernel(
    const float* __restrict__ w1, const float* __restrict__ w2,
    short* __restrict__ Hpk, const int* __restrict__ adj_row,
    const int* __restrict__ adj_col, const float* __restrict__ adj_val,
    int* __restrict__ rowptr, uint2* __restrict__ cv, int E, int N) {
  if (blockIdx.x < 16) {
    int idx = blockIdx.x * 256 + threadIdx.x;  // 4096: (m,kt,ct,lane)
    int m = idx >> 11;
    int kt = (idx >> 9) & 3;
    int ct = (idx >> 6) & 7;
    int l = idx & 63;
    int col = ct * 16 + (l & 15);
    const float* w = m ? w2 : w1;
    short hi[8], lo[8];
#pragma unroll
    for (int j = 0; j < 8; ++j) {
      int row = kt * 32 + (l >> 4) * 8 + j;  // k index of B
      int rb = row >> 5, cb = col >> 5;
      int neg = (0x284E >> (cb * 4 + rb)) & 1;
      float v = w[(row & 31) * 128 + (rb ^ cb) * 32 + (col & 31)];
      v = neg ? -v : v;
      short h = f2bf(v);
      hi[j] = h;
      lo[j] = f2bf(v - bf2f(h));
    }
    size_t b0 = ((((size_t)m * 2 + 0) * 4 + kt) * 8 + ct) * 64 + l;
    size_t b1 = ((((size_t)m * 2 + 1) * 4 + kt) * 8 + ct) * 64 + l;
    *(short8*)&Hpk[b0 * 8] = *(short8*)hi;
    *(short8*)&Hpk[b1 * 8] = *(short8*)lo;
  } else {
    int e = (blockIdx.x - 16) * 256 + threadIdx.x;
    if (e >= E) return;
    cv[e] = make_uint2((uint32_t)adj_col[e], __float_as_uint(adj_val[e]));
    int r = adj_row[e];
    int rprev = (e == 0) ? -1 : adj_row[e - 1];
    for (int q = rprev + 1; q <= r; ++q) rowptr[q] = e;
    if (e == E - 1) {
      for (int q = r + 1; q <= N; ++q) rowptr[q] = E;
    }
  }
}

// ---------------- fused MFMA GEMM: out2 = tanh(X @ H1) @ H2, bf16 out ----------------
// 256 threads (4 waves x 16 rows). B-frags staged in shared LDS in 32 KB
// HALF-matrix phases (kt-pairs) -> 49.4 KB LDS total -> 3 blocks/CU.
__global__ __launch_bounds__(256) void gemm_mfma(
    const float* __restrict__ input, const short* __restrict__ Hpk,
    short* __restrict__ out2b, int N) {
  __shared__ short Hs[16384];         // 32 KB: half-matrix frags [part][ktl][ct][lane][j]
  __shared__ short lds[4][16 * LDK];  // 17.4 KB per-wave hid tiles
  const int t = threadIdx.x;
  const int w = t >> 6, l = t & 63;
  const int lr = l & 15, lg = l >> 4;
  const int grow0 = blockIdx.x * 64 + w * 16;
  short* hid = &lds[w][0];

#define STAGE_HALF(m, P)                                             \
  {                                                                  \
    const int base = ((m) * 8 + 2 * (P)) * 512;                      \
    _Pragma("unroll") for (int i = 0; i < 8; ++i) {                  \
      int idx = i * 256 + t;                                         \
      int src = idx + base + (idx >> 10) * 1024;                     \
      *(short8*)&Hs[idx * 8] = *(const short8*)&Hpk[src * 8];        \
    }                                                                \
  }

#define GEMM_HALF(afrag, P)                                                          \
  {                                                                                  \
    _Pragma("unroll") for (int ktl = 0; ktl < 2; ++ktl) {                            \
      _Pragma("unroll") for (int ct = 0; ct < 8; ++ct) {                             \
        short8 bh = *(const short8*)&Hs[((ktl * 8 + ct) * 64 + l) * 8];              \
        short8 bl = *(const short8*)&Hs[(((2 + ktl) * 8 + ct) * 64 + l) * 8];        \
        acc[ct] = __builtin_amdgcn_mfma_f32_16x16x32_bf16(afrag[2 * (P) + ktl], bl,  \
                                                          acc[ct], 0, 0, 0);         \
        acc[ct] = __builtin_amdgcn_mfma_f32_16x16x32_bf16(afrag[2 * (P) + ktl], bh,  \
                                                          acc[ct], 0, 0, 0);         \
      }                                                                              \
    }                                                                                \
  }

  // A1 fragments (hi only) from global f32
  short8 a1h[4];
  {
    int arow = grow0 + lr;
    if (arow >= N) arow = N - 1;
    const float* xr = &input[(size_t)arow * F];
#pragma unroll
    for (int kt = 0; kt < 4; ++kt) {
      float xv[8];
      *(float4*)&xv[0] = *(const float4*)&xr[kt * 32 + lg * 8];
      *(float4*)&xv[4] = *(const float4*)&xr[kt * 32 + lg * 8 + 4];
#pragma unroll
      for (int j = 0; j < 8; ++j) ((short*)&a1h[kt])[j] = f2bf(xv[j]);
    }
  }

  f32x4 acc[8];
#pragma unroll
  for (int ct = 0; ct < 8; ++ct) acc[ct] = (f32x4){0.f, 0.f, 0.f, 0.f};

  STAGE_HALF(0, 0)
  __syncthreads();
  GEMM_HALF(a1h, 0)
  __syncthreads();
  STAGE_HALF(0, 1)
  __syncthreads();
  GEMM_HALF(a1h, 1)

  // hid = tanh(acc) -> per-wave LDS row-major (C layout: row=lg*4+r, col=ct*16+lr)
#pragma unroll
  for (int ct = 0; ct < 8; ++ct)
#pragma unroll
    for (int r = 0; r < 4; ++r)
      hid[(lg * 4 + r) * LDK + ct * 16 + lr] = f2bf(tanhf(acc[ct][r]));

  // A2 fragments: vectorized b128 reads from own wave's tile (row=lr, k contiguous)
  short8 a2h[4];
#pragma unroll
  for (int kt = 0; kt < 4; ++kt)
    a2h[kt] = *(short8*)&hid[lr * LDK + kt * 32 + lg * 8];

#pragma unroll
  for (int ct = 0; ct < 8; ++ct) acc[ct] = (f32x4){0.f, 0.f, 0.f, 0.f};

  __syncthreads();  // all waves done reading H1 half
  STAGE_HALF(1, 0)
  __syncthreads();
  GEMM_HALF(a2h, 0)
  __syncthreads();
  STAGE_HALF(1, 1)
  __syncthreads();
  GEMM_HALF(a2h, 1)

  // epilogue: bf16 pack -> per-wave LDS, then coalesced row stores
#pragma unroll
  for (int ct = 0; ct < 8; ++ct)
#pragma unroll
    for (int r = 0; r < 4; ++r)
      hid[(lg * 4 + r) * LDK + ct * 16 + lr] = f2bf(acc[ct][r]);
#pragma unroll
  for (int i = 0; i < 4; ++i) {
    int chunk = i * 64 + l;
    int row = chunk >> 4, pos = chunk & 15;
    int grow = grow0 + row;
    if (grow < N)
      *(short8*)&out2b[(size_t)grow * F + pos * 8] = *(short8*)&hid[row * LDK + pos * 8];
  }
#undef STAGE_HALF
#undef GEMM_HALF
}

// ---------------- segment-sum SpMM + fused BN stats ----------------
// 2 rows/wave interleaved (8 gathers in flight); 16 lanes/edge dwordx4; clamped
// quads; next-pair rowptr prefetch; grid-stride over row pairs.
__global__ __launch_bounds__(256) void agg_rows7(
    const uint32_t* __restrict__ out2u, const int* __restrict__ rowptr,
    const uint2* __restrict__ cv, float* __restrict__ agg,
    float* __restrict__ partials, int N) {
  const int t = threadIdx.x;
  const int w = t >> 6, lane = t & 63;
  const int sub = lane >> 4;
  const int fl4 = (lane & 15) * 4;
  const int wid = blockIdx.x * 4 + w;
  const int nw = gridDim.x * 4;
  float ssum[8], ssq[8];
#pragma unroll
  for (int j = 0; j < 8; ++j) { ssum[j] = 0.f; ssq[j] = 0.f; }

  int pr = wid;
  bool active = pr * 2 < N;
  int sA = 0, eAe = 0, eBe = 0;
  if (active) {
    sA = rowptr[pr * 2];
    eAe = rowptr[pr * 2 + 1];
    eBe = (pr * 2 + 1 < N) ? rowptr[pr * 2 + 2] : eAe;
  }
  while (active) {
    const int prn = pr + nw;
    const bool actn = prn * 2 < N;
    int sAn = 0, eAen = 0, eBen = 0;
    if (actn) {
      sAn = rowptr[prn * 2];
      eAen = rowptr[prn * 2 + 1];
      eBen = (prn * 2 + 1 < N) ? rowptr[prn * 2 + 2] : eAen;
    }
    const int rowA = pr * 2;
    const bool hasB = rowA + 1 < N;
    const int sB = eAe;

    float accA[8], accB[8];
#pragma unroll
    for (int j = 0; j < 8; ++j) { accA[j] = 0.f; accB[j] = 0.f; }

    int eA = sA, eB = sB;
    while (eA < eAe || eB < eBe) {
      float vA[4], vB[4];
      uint32_t cA[4], cB[4];
#pragma unroll
      for (int q = 0; q < 4; ++q) {
        int ee = eA + q * 4 + sub;
        bool val = ee < eAe;
        int idx = val ? ee : (eAe - 1);
        idx = idx < 0 ? 0 : idx;
        uint2 p = cv[idx];
        cA[q] = p.x;
        vA[q] = val ? __uint_as_float(p.y) : 0.f;
      }
#pragma unroll
      for (int q = 0; q < 4; ++q) {
        int ee = eB + q * 4 + sub;
        bool val = ee < eBe;
        int idx = val ? ee : (eBe - 1);
        idx = idx < 0 ? 0 : idx;
        uint2 p = cv[idx];
        cB[q] = p.x;
        vB[q] = val ? __uint_as_float(p.y) : 0.f;
      }
      uint4 uA[4], uB[4];
#pragma unroll
      for (int q = 0; q < 4; ++q)
        uA[q] = *(const uint4*)&out2u[(size_t)(cA[q] * 64u + fl4)];
#pragma unroll
      for (int q = 0; q < 4; ++q)
        uB[q] = *(const uint4*)&out2u[(size_t)(cB[q] * 64u + fl4)];
#pragma unroll
      for (int q = 0; q < 4; ++q) {
#pragma unroll
        for (int k = 0; k < 4; ++k) {
          uint32_t ua = ((const uint32_t*)&uA[q])[k];
          uint32_t ub = ((const uint32_t*)&uB[q])[k];
          accA[2 * k]     = fmaf(vA[q], __uint_as_float(ua << 16), accA[2 * k]);
          accA[2 * k + 1] = fmaf(vA[q], __uint_as_float(ua & 0xFFFF0000u), accA[2 * k + 1]);
          accB[2 * k]     = fmaf(vB[q], __uint_as_float(ub << 16), accB[2 * k]);
          accB[2 * k + 1] = fmaf(vB[q], __uint_as_float(ub & 0xFFFF0000u), accB[2 * k + 1]);
        }
      }
      eA += 16;
      eB += 16;
    }
#pragma unroll
    for (int j = 0; j < 8; ++j) {
      accA[j] += __shfl_xor(accA[j], 16, 64);
      accA[j] += __shfl_xor(accA[j], 32, 64);
      accB[j] += __shfl_xor(accB[j], 16, 64);
      accB[j] += __shfl_xor(accB[j], 32, 64);
    }
    if (sub == 0) {
      *(float4*)&agg[(size_t)rowA * F + fl4 * 2] = make_float4(accA[0], accA[1], accA[2], accA[3]);
      *(float4*)&agg[(size_t)rowA * F + fl4 * 2 + 4] = make_float4(accA[4], accA[5], accA[6], accA[7]);
#pragma unroll
      for (int j = 0; j < 8; ++j) {
        ssum[j] += accA[j];
        ssq[j] = fmaf(accA[j], accA[j], ssq[j]);
      }
      if (hasB) {
        *(float4*)&agg[(size_t)(rowA + 1) * F + fl4 * 2] = make_float4(accB[0], accB[1], accB[2], accB[3]);
        *(float4*)&agg[(size_t)(rowA + 1) * F + fl4 * 2 + 4] = make_float4(accB[4], accB[5], accB[6], accB[7]);
#pragma unroll
        for (int j = 0; j < 8; ++j) {
          ssum[j] += accB[j];
          ssq[j] = fmaf(accB[j], accB[j], ssq[j]);
        }
      }
    }
    pr = prn;
    sA = sAn; eAe = eAen; eBe = eBen;
    active = actn;
  }

  __shared__ float ls[4][128];
  __shared__ float lq[4][128];
  if (sub == 0) {
#pragma unroll
    for (int j = 0; j < 8; ++j) {
      ls[w][fl4 * 2 + j] = ssum[j];
      lq[w][fl4 * 2 + j] = ssq[j];
    }
  }
  __syncthreads();
  if (t < 128) {
    float S = ls[0][t] + ls[1][t] + ls[2][t] + ls[3][t];
    float Q = lq[0][t] + lq[1][t] + lq[2][t] + lq[3][t];
    float* dst = &partials[(size_t)blockIdx.x * 256];
    dst[t] = S;
    dst[128 + t] = Q;
  }
}

// ---------------- stats mid-reduce: nb slices -> MID_BLOCKS slices ----------------
__global__ __launch_bounds__(256) void mid_reduce(
    const float* __restrict__ partials, float* __restrict__ mid, int nb) {
  const int k = blockIdx.x, t = threadIdx.x;
  const int per = nb / MID_BLOCKS;
  float s = 0.f;
#pragma unroll 4
  for (int i = 0; i < per; ++i)
    s += partials[(size_t)(k * per + i) * 256 + t];
  mid[(size_t)k * 256 + t] = s;
}

// ---------------- finalize: reduce mid, produce scale/shift ----------------
__global__ __launch_bounds__(256) void finalize_stats3(
    const float* __restrict__ mid, const float* __restrict__ gamma,
    const float* __restrict__ beta, float* __restrict__ ss, float invN) {
  const int t = threadIdx.x;  // 256
  float s = 0.f;
#pragma unroll 8
  for (int b = 0; b < MID_BLOCKS; ++b) s += mid[(size_t)b * 256 + t];
  __shared__ float tot[256];
  tot[t] = s;
  __syncthreads();
  if (t < 128) {
    float mean = tot[t] * invN;
    float var = tot[128 + t] * invN - mean * mean;
    float inv = rsqrtf(var + 1e-5f);
    float sc = gamma[t] * inv;
    ss[t] = sc;
    ss[128 + t] = beta[t] - mean * sc;
  }
}

__global__ __launch_bounds__(256) void bn_apply(
    float* __restrict__ out, const float* __restrict__ ss, int total4) {
  int idx = blockIdx.x * 256 + threadIdx.x;
  if (idx >= total4) return;
  int f4 = (idx & 31) * 4;
  float4 v = *(float4*)&out[(size_t)idx * 4];
  float4 sc = *(const float4*)&ss[f4];
  float4 sh = *(const float4*)&ss[128 + f4];
  v.x = fmaf(v.x, sc.x, sh.x);
  v.y = fmaf(v.y, sc.y, sh.y);
  v.z = fmaf(v.z, sc.z, sh.z);
  v.w = fmaf(v.w, sc.w, sh.w);
  *(float4*)&out[(size_t)idx * 4] = v;
}

// ---------------- launch ----------------
// ws layout (bytes):
//   [0,        131072)   Hpk bf16 fragments (128 KB)
//   [131072,   132096)   ss: scale[128], shift[128]
//   [132096,   2229248)  partials (AGG_BLOCKS x 256 floats, 2 MB)
//   [2229248,  2294784)  mid: MID_BLOCKS x 256 floats
//   [2294784,  2499584)  rowptr (N+1 ints, padded)
//   [2499584,  +E*8)     cv pairs (col,val) per edge
//   [then]               out2 bf16 [N*128]
extern "C" void kernel_launch(void* const* d_in, const int* in_sizes, int n_in,
                              void* d_out, int out_size, void* d_ws, size_t ws_size,
                              hipStream_t stream) {
  (void)n_in; (void)out_size; (void)ws_size;
  const float* input  = (const float*)d_in[0];
  const int*  adj_row = (const int*)d_in[1];
  const int*  adj_col = (const int*)d_in[2];
  const float* adj_val = (const float*)d_in[3];
  const float* w1 = (const float*)d_in[4];
  const float* w2 = (const float*)d_in[5];
  const float* gamma = (const float*)d_in[6];
  const float* beta  = (const float*)d_in[7];
  const int N = in_sizes[0] / F;
  const int E = in_sizes[1];

  char* ws = (char*)d_ws;
  short* Hpk = (short*)(ws);
  float* ss = (float*)(ws + 131072);
  float* partials = (float*)(ws + 132096);
  float* mid = (float*)(ws + 2229248);
  int* rowptr = (int*)(ws + 2294784);
  uint2* cv = (uint2*)(ws + 2499584);
  size_t cv_bytes = ((size_t)E * 8 + 511) & ~(size_t)511;
  short* out2b = (short*)(ws + 2499584 + cv_bytes);
  float* agg = (float*)d_out;

  setup_kernel<<<16 + (E + 255) / 256, 256, 0, stream>>>(
      w1, w2, Hpk, adj_row, adj_col, adj_val, rowptr, cv, E, N);
  gemm_mfma<<<(N + 63) / 64, 256, 0, stream>>>(input, Hpk, out2b, N);
  agg_rows7<<<AGG_BLOCKS, 256, 0, stream>>>(
      (const uint32_t*)out2b, rowptr, cv, agg, partials, N);
  mid_reduce<<<MID_BLOCKS, 256, 0, stream>>>(partials, mid, AGG_BLOCKS);
  finalize_stats3<<<1, 256, 0, stream>>>(mid, gamma, beta, ss, 1.0f / (float)N);
  bn_apply<<<(N * 32 + 255) / 256, 256, 0, stream>>>(agg, ss, N * 32);
}